// Round 3
// baseline (337.951 us; speedup 1.0000x reference)
//
#include <hip/hip_runtime.h>
#include <stdint.h>

typedef int v4i  __attribute__((ext_vector_type(4)));
typedef int v16i __attribute__((ext_vector_type(16)));

// direct global->LDS DMA, 16B per lane. LDS dest = wave-uniform base + lane*16.
__device__ __forceinline__ void gll16(const void* g, void* l) {
    __builtin_amdgcn_global_load_lds(
        (const __attribute__((address_space(1))) void*)(uintptr_t)g,
        (__attribute__((address_space(3))) void*)(uint32_t)(uintptr_t)l,
        16, 0, 0);
}

// ---------------- Kernel 1: quantize x rows (blocks < Mpad) + convert w rows ----------------
// blocks [0, Mpad): per-row dynamic int8 quant of x (rows >= M zero-padded).
// blocks [Mpad, Mpad+D_OUT): convert one w_int row (int32 -> int8).
__global__ __launch_bounds__(256) void prep(const float* __restrict__ x,
                                            const int* __restrict__ w,
                                            signed char* __restrict__ xq,
                                            signed char* __restrict__ w8,
                                            float* __restrict__ sx,
                                            int M, int Mpad) {
    const int b = blockIdx.x;
    const int tid = threadIdx.x;
    if (b >= Mpad) {  // w conversion: row = b - Mpad, 1024 int32 -> 1024 int8
        const int r = b - Mpad;
        const int4 v = ((const int4*)(w + (size_t)r * 1024))[tid];
        char4 c;
        c.x = (signed char)v.x; c.y = (signed char)v.y;
        c.z = (signed char)v.z; c.w = (signed char)v.w;
        ((char4*)(w8 + (size_t)r * 1024))[tid] = c;
        return;
    }
    signed char* qrow = xq + (size_t)b * 1024;
    if (b >= M) {  // zero pad rows
        ((char4*)qrow)[tid] = make_char4(0, 0, 0, 0);
        if (tid == 0) sx[b] = 0.0f;
        return;
    }
    const float4 v = ((const float4*)(x + (size_t)b * 1024))[tid];
    float a = fmaxf(fmaxf(fabsf(v.x), fabsf(v.y)), fmaxf(fabsf(v.z), fabsf(v.w)));
#pragma unroll
    for (int off = 32; off > 0; off >>= 1)
        a = fmaxf(a, __shfl_xor(a, off));
    __shared__ float red[4];
    if ((tid & 63) == 0) red[tid >> 6] = a;
    __syncthreads();
    const float am = fmaxf(fmaxf(red[0], red[1]), fmaxf(red[2], red[3]));
    const float amc = fmaxf(am, 1e-8f);
    const float inv = 127.0f / amc;
    char4 q;
    q.x = (signed char)(int)rintf(v.x * inv);
    q.y = (signed char)(int)rintf(v.y * inv);
    q.z = (signed char)(int)rintf(v.z * inv);
    q.w = (signed char)(int)rintf(v.w * inv);
    ((char4*)qrow)[tid] = q;
    if (tid == 0) sx[b] = amc * (1.0f / 127.0f);
}

// ---------------- Kernel 2: int8 GEMM (128x128 tile, BK=128) + fused dequant ----------------
// C[m][n] = sum_k xq[m][k] * w8[n][k]; 4 waves/block, each wave a 64x64 subtile
// built from 2x2 mfma_i32_32x32x32_i8 tiles over 4 K-substeps per LDS slab.
// 8 K-iterations total (vs 16 at BK=64) -> half the full-barrier drains.
//
// LDS rows are 128B; the eight 16B chunks of row r are XOR-swizzled by key r&7.
// Swizzle applied on the GLOBAL fetch side (global_load_lds can't scatter);
// staging key folds to (t>>3)&7 (issue-invariant), fragment key to lane&7.
__global__ __launch_bounds__(256) void gemm_i8(const signed char* __restrict__ xq,
                                               const signed char* __restrict__ w8,
                                               const float* __restrict__ sx,
                                               const float* __restrict__ sw,
                                               const float* __restrict__ bias,
                                               float* __restrict__ out,
                                               int M, int N, int K) {
    __shared__ signed char As[128 * 128];
    __shared__ signed char Bs[128 * 128];

    const int tid  = threadIdx.x;
    const int lane = tid & 63;
    const int wave = tid >> 6;
    const int wm = (wave & 1) * 64;
    const int wn = (wave >> 1) * 64;
    const int m_block = blockIdx.y * 128;
    const int n_block = blockIdx.x * 128;

    v16i acc[2][2];
#pragma unroll
    for (int mt = 0; mt < 2; ++mt)
#pragma unroll
        for (int nt = 0; nt < 2; ++nt)
#pragma unroll
            for (int r = 0; r < 16; ++r)
                acc[mt][nt][r] = 0;

    // staging: thread t, issue i covers LDS bytes [i*4096 + t*16, +16).
    // row = (t>>3) + 32*i, LDS chunk = t&7, global chunk = (t&7) ^ ((t>>3)&7).
    const int trow   = tid >> 3;                         // 0..31
    const int tchunk = ((tid & 7) ^ (trow & 7)) * 16;    // swizzled global chunk offset
    const signed char* aG = xq + (size_t)(m_block + trow) * K + tchunk;
    const signed char* bG = w8 + (size_t)(n_block + trow) * K + tchunk;
    const size_t rowstep = (size_t)32 * K;
    signed char* aL = As + wave * 1024;   // + i*4096 per issue
    signed char* bL = Bs + wave * 1024;

    const int fr = lane & 31;   // fragment row (m or n)
    const int fk = lane >> 5;   // K half-chunk selector
    const int fx = lane & 7;    // fragment unswizzle key

    for (int k0 = 0; k0 < K; k0 += 128) {
        if (k0) __syncthreads();
#pragma unroll
        for (int i = 0; i < 4; ++i) {
            gll16(aG + k0 + i * rowstep, aL + i * 4096);
            gll16(bG + k0 + i * rowstep, bL + i * 4096);
        }
        __syncthreads();  // drains vmcnt(0): LDS slabs complete & visible

#pragma unroll
        for (int kk = 0; kk < 4; ++kk) {
            const int coff = ((kk * 2 + fk) ^ fx) * 16;  // unswizzled chunk byte offset
            v4i af[2], bf[2];
#pragma unroll
            for (int mt = 0; mt < 2; ++mt)
                af[mt] = *(const v4i*)&As[(wm + mt * 32 + fr) * 128 + coff];
#pragma unroll
            for (int nt = 0; nt < 2; ++nt)
                bf[nt] = *(const v4i*)&Bs[(wn + nt * 32 + fr) * 128 + coff];
#pragma unroll
            for (int mt = 0; mt < 2; ++mt)
#pragma unroll
                for (int nt = 0; nt < 2; ++nt)
                    acc[mt][nt] = __builtin_amdgcn_mfma_i32_32x32x32_i8(af[mt], bf[nt], acc[mt][nt], 0, 0, 0);
        }
    }

    // epilogue: 32x32 C/D layout col=lane&31, row=(reg&3)+8*(reg>>2)+4*(lane>>5)
    const int lc = lane & 31;
    const int lh = (lane >> 5) * 4;
#pragma unroll
    for (int mt = 0; mt < 2; ++mt) {
        const int rbase = m_block + wm + mt * 32 + lh;
        float sxv[16];
#pragma unroll
        for (int r = 0; r < 16; ++r) {
            const int row = rbase + (r & 3) + 8 * (r >> 2);
            sxv[r] = (row < M) ? sx[row] : 0.0f;
        }
#pragma unroll
        for (int nt = 0; nt < 2; ++nt) {
            const int col = n_block + wn + nt * 32 + lc;
            const float sww = sw[col];
            const float bv  = bias[col];
#pragma unroll
            for (int r = 0; r < 16; ++r) {
                const int row = rbase + (r & 3) + 8 * (r >> 2);
                if (row < M)
                    out[(size_t)row * N + col] = (float)acc[mt][nt][r] * sxv[r] * sww + bv;
            }
        }
    }
}

extern "C" void kernel_launch(void* const* d_in, const int* in_sizes, int n_in,
                              void* d_out, int out_size, void* d_ws, size_t ws_size,
                              hipStream_t stream) {
    const float* x       = (const float*)d_in[0];
    const int*   w_int   = (const int*)d_in[1];
    const float* scale_w = (const float*)d_in[2];
    const float* bias    = (const float*)d_in[3];
    float* out = (float*)d_out;

    const int D_OUT = in_sizes[2];             // 2560
    const int D_IN  = in_sizes[1] / D_OUT;     // 1024
    const int M     = in_sizes[0] / D_IN;      // 18464
    const int Mpad  = ((M + 127) / 128) * 128; // 18560

    // workspace layout (all 16B-aligned):
    signed char* xq = (signed char*)d_ws;                      // Mpad * D_IN  int8
    signed char* w8 = xq + (size_t)Mpad * D_IN;                // D_OUT * D_IN int8
    float*       sx = (float*)(w8 + (size_t)D_OUT * D_IN);     // Mpad floats

    prep<<<Mpad + D_OUT, 256, 0, stream>>>(x, w_int, xq, w8, sx, M, Mpad);
    dim3 grid(D_OUT / 128, Mpad / 128);  // (20, 145): x-major sweeps N for one M-row -> A-tile L2 reuse
    gemm_i8<<<grid, dim3(256, 1, 1), 0, stream>>>(xq, w8, sx, scale_w, bias, out, M, D_OUT, D_IN);
}

// Round 4
// 324.995 us; speedup vs baseline: 1.0399x; 1.0399x over previous
//
#include <hip/hip_runtime.h>
#include <stdint.h>

typedef int v4i __attribute__((ext_vector_type(4)));

// ---------------- prep: quantize x and convert w, writing MFMA-fragment-packed int8 ----------
// Packed layout (identical for A and B): for 16-row group g, K-block kb (64 k's),
// 16B unit (c = k-chunk 0..3, r = row 0..15) lives at byte offset
//     (g*16 + kb)*1024 + c*256 + r*16
// so a GEMM wave's fragment load is exactly  base + lane*16  (lane = c*16 + r),
// i.e. one perfectly-coalesced global_load_dwordx4 per fragment.
//
// blocks [0, MGpad): x-groups (quantize 16 rows); blocks [MGpad, MGpad+NG): w-groups.
// thread t: r = t>>4 (row in group), s = t&15 (k-segment of 64 = kb).
__global__ __launch_bounds__(256) void prep(const float* __restrict__ x,
                                            const int* __restrict__ w,
                                            signed char* __restrict__ xqp,
                                            signed char* __restrict__ w8p,
                                            float* __restrict__ sx,
                                            int M, int MGpad) {
    const int b = blockIdx.x;
    const int t = threadIdx.x;
    const int r = t >> 4;
    const int s = t & 15;

    if (b >= MGpad) {  // ---- w conversion group ----
        const int g = b - MGpad;
        const int row = g * 16 + r;
        const int4* src = (const int4*)(w + (size_t)row * 1024 + s * 64);
        signed char* dst = w8p + (((size_t)(g * 16 + s)) << 10) + r * 16;
        int4 v[16];
#pragma unroll
        for (int i = 0; i < 16; ++i) v[i] = src[i];
#pragma unroll
        for (int c = 0; c < 4; ++c) {
            int4 u;
            uint32_t wds[4];
#pragma unroll
            for (int q = 0; q < 4; ++q) {  // word q packs elements c*16+q*4 .. +3
                const int4 e = v[c * 4 + q];
                wds[q] = ((uint32_t)(uint8_t)(signed char)e.x) |
                         ((uint32_t)(uint8_t)(signed char)e.y << 8) |
                         ((uint32_t)(uint8_t)(signed char)e.z << 16) |
                         ((uint32_t)(uint8_t)(signed char)e.w << 24);
            }
            u.x = wds[0]; u.y = wds[1]; u.z = wds[2]; u.w = wds[3];
            *(int4*)(dst + c * 256) = u;
        }
        return;
    }

    // ---- x quantization group ----
    const int row = b * 16 + r;
    float4 f[16];
    if (row < M) {
        const float4* src = (const float4*)(x + (size_t)row * 1024 + s * 64);
#pragma unroll
        for (int i = 0; i < 16; ++i) f[i] = src[i];
    } else {
#pragma unroll
        for (int i = 0; i < 16; ++i) f[i] = make_float4(0.f, 0.f, 0.f, 0.f);
    }
    float am = 0.0f;
#pragma unroll
    for (int i = 0; i < 16; ++i)
        am = fmaxf(am, fmaxf(fmaxf(fabsf(f[i].x), fabsf(f[i].y)),
                             fmaxf(fabsf(f[i].z), fabsf(f[i].w))));
    // butterfly over the 16 contiguous lanes of this row (s = lane&15)
#pragma unroll
    for (int off = 1; off < 16; off <<= 1)
        am = fmaxf(am, __shfl_xor(am, off));
    const float amc = fmaxf(am, 1e-8f);
    const float inv = 127.0f / amc;
    if (s == 0) sx[row] = amc * (1.0f / 127.0f);

    signed char* dst = xqp + (((size_t)(b * 16 + s)) << 10) + r * 16;
#pragma unroll
    for (int c = 0; c < 4; ++c) {
        int4 u;
        uint32_t wds[4];
#pragma unroll
        for (int q = 0; q < 4; ++q) {
            const float4 e = f[c * 4 + q];
            wds[q] = ((uint32_t)(uint8_t)(signed char)(int)rintf(e.x * inv)) |
                     ((uint32_t)(uint8_t)(signed char)(int)rintf(e.y * inv) << 8) |
                     ((uint32_t)(uint8_t)(signed char)(int)rintf(e.z * inv) << 16) |
                     ((uint32_t)(uint8_t)(signed char)(int)rintf(e.w * inv) << 24);
        }
        u.x = wds[0]; u.y = wds[1]; u.z = wds[2]; u.w = wds[3];
        *(int4*)(dst + c * 256) = u;
    }
}

// ---------------- GEMM: barrier-free, LDS-free, fragment-packed operands ----------------
// 128x128 tile, 4 waves, each wave a 64x64 subtile of 4x4 16x16x64 i8 MFMAs.
// Fragments load directly from global (packed layout -> base + lane*16, 1KB coalesced).
// No __syncthreads anywhere: the compiler pipelines loads across the unrolled K-loop
// with fine-grained vmcnt(N) — no full-drain barriers.
__global__ __launch_bounds__(256, 3) void gemm_i8(const signed char* __restrict__ ap,
                                                  const signed char* __restrict__ bp,
                                                  const float* __restrict__ sx,
                                                  const float* __restrict__ sw,
                                                  const float* __restrict__ bias,
                                                  float* __restrict__ out,
                                                  int M, int N, int KB) {
    const int tid  = threadIdx.x;
    const int lane = tid & 63;
    const int wave = tid >> 6;
    const int wm = (wave & 1) * 64;
    const int wn = (wave >> 1) * 64;
    const int m_block = blockIdx.y * 128;
    const int n_block = blockIdx.x * 128;

    // fragment base pointers: group (ga+mt) / (gb+nt), each group = 16KB (16 kb * 1KB)
    const signed char* aBase = ap + (((size_t)((m_block + wm) >> 4)) << 14) + lane * 16;
    const signed char* bBase = bp + (((size_t)((n_block + wn) >> 4)) << 14) + lane * 16;

    v4i acc[4][4];
#pragma unroll
    for (int mt = 0; mt < 4; ++mt)
#pragma unroll
        for (int nt = 0; nt < 4; ++nt) {
            acc[mt][nt].x = 0; acc[mt][nt].y = 0; acc[mt][nt].z = 0; acc[mt][nt].w = 0;
        }

#pragma unroll 16
    for (int kb = 0; kb < KB; ++kb) {
        v4i af[4], bf[4];
#pragma unroll
        for (int mt = 0; mt < 4; ++mt)
            af[mt] = *(const v4i*)(aBase + (size_t)mt * 16384 + (size_t)kb * 1024);
#pragma unroll
        for (int nt = 0; nt < 4; ++nt)
            bf[nt] = *(const v4i*)(bBase + (size_t)nt * 16384 + (size_t)kb * 1024);
#pragma unroll
        for (int mt = 0; mt < 4; ++mt)
#pragma unroll
            for (int nt = 0; nt < 4; ++nt)
                acc[mt][nt] = __builtin_amdgcn_mfma_i32_16x16x64_i8(af[mt], bf[nt], acc[mt][nt], 0, 0, 0);
    }

    // epilogue: C/D layout col=lane&15, row=(lane>>4)*4+reg (dtype-independent)
    const int lr = lane >> 4;
    const int lc = lane & 15;
#pragma unroll
    for (int mt = 0; mt < 4; ++mt) {
        const int rbase = m_block + wm + mt * 16 + lr * 4;
        float sxv[4];
#pragma unroll
        for (int r = 0; r < 4; ++r)
            sxv[r] = (rbase + r < M) ? sx[rbase + r] : 0.0f;
#pragma unroll
        for (int nt = 0; nt < 4; ++nt) {
            const int col = n_block + wn + nt * 16 + lc;
            const float swv = sw[col];
            const float bv  = bias[col];
            const int* a = (const int*)&acc[mt][nt];
#pragma unroll
            for (int r = 0; r < 4; ++r) {
                const int row = rbase + r;
                if (row < M)
                    out[(size_t)row * N + col] = (float)a[r] * sxv[r] * swv + bv;
            }
        }
    }
}

extern "C" void kernel_launch(void* const* d_in, const int* in_sizes, int n_in,
                              void* d_out, int out_size, void* d_ws, size_t ws_size,
                              hipStream_t stream) {
    const float* x       = (const float*)d_in[0];
    const int*   w_int   = (const int*)d_in[1];
    const float* scale_w = (const float*)d_in[2];
    const float* bias    = (const float*)d_in[3];
    float* out = (float*)d_out;

    const int D_OUT = in_sizes[2];             // 2560
    const int D_IN  = in_sizes[1] / D_OUT;     // 1024
    const int M     = in_sizes[0] / D_IN;      // 18464
    const int Mpad  = ((M + 127) / 128) * 128; // 18560
    const int MGpad = Mpad / 16;               // 1160 row-groups
    const int NG    = D_OUT / 16;              // 160 row-groups
    const int KB    = D_IN / 64;               // 16 K-blocks

    // workspace layout (16B-aligned):
    signed char* xqp = (signed char*)d_ws;                       // Mpad * D_IN  int8 (packed)
    signed char* w8p = xqp + (size_t)Mpad * D_IN;                // D_OUT * D_IN int8 (packed)
    float*       sx  = (float*)(w8p + (size_t)D_OUT * D_IN);     // Mpad floats

    prep<<<MGpad + NG, 256, 0, stream>>>(x, w_int, xqp, w8p, sx, M, MGpad);
    dim3 grid(D_OUT / 128, Mpad / 128);  // (20, 145)
    gemm_i8<<<grid, dim3(256, 1, 1), 0, stream>>>(xqp, w8p, sx, scale_w, bias, out, M, D_OUT, KB);
}